// Round 5
// baseline (142.687 us; speedup 1.0000x reference)
//
#include <hip/hip_runtime.h>

typedef __attribute__((ext_vector_type(4))) float f32x4;
typedef __attribute__((ext_vector_type(8))) float f32x8;
typedef __attribute__((ext_vector_type(8))) short bf16x8;

#define S_LEN 4096

__device__ inline short f2bf(float f) {
    union { float f; unsigned u; } v; v.f = f;
    unsigned r = (v.u + 0x7fffu + ((v.u >> 16) & 1u)) >> 16;
    return (short)r;
}
__device__ inline unsigned pack2bf(float a, float b) {
    return (unsigned)(unsigned short)f2bf(a) | ((unsigned)(unsigned short)f2bf(b) << 16);
}

// Wt[g][k], g = m*64 + c (m: 0=Q,1=K,2=V), from W_m[k][c] (fp32 [1024][64])
__global__ __launch_bounds__(256) void wconv_kernel(const float* __restrict__ Wq,
        const float* __restrict__ Wk, const float* __restrict__ Wv,
        short* __restrict__ Wt) {
    int idx = blockIdx.x * 256 + threadIdx.x;
    int m = idx >> 16, c = (idx >> 10) & 63, k = idx & 1023;
    const float* W = (m == 0) ? Wq : (m == 1) ? Wk : Wv;
    Wt[idx] = f2bf(W[k * 64 + c]);
}

// Barrier-free: 256 thr = 4 waves; block owns 16 rows; wave w -> cols [w*48, w*48+48).
// All 4 waves read the same x rows -> L1 dedups; B-frags stream from L2-hot Wt.
__global__ __launch_bounds__(256, 4) void qkv_kernel(const float* __restrict__ x,
        const short* __restrict__ Wt, short* __restrict__ Qb,
        short* __restrict__ Kb, short* __restrict__ Vt) {
    const int tid = threadIdx.x;
    const int wv = tid >> 6, lane = tid & 63;
    const int lr = lane & 15, lg = lane >> 4;
    const int rowbase = blockIdx.x * 16;

    f32x4 acc[3];
#pragma unroll
    for (int i = 0; i < 3; i++) acc[i] = {0.f, 0.f, 0.f, 0.f};

    const float* xrow  = x + (size_t)(rowbase + lr) * 1024 + lg * 8;
    const short* wbase = Wt + (size_t)(wv * 48 + lr) * 1024 + lg * 8;

#pragma unroll 4
    for (int k0 = 0; k0 < 1024; k0 += 32) {
        f32x8 xf = *(const f32x8*)(xrow + k0);
        bf16x8 a;
#pragma unroll
        for (int jj = 0; jj < 8; jj++) a[jj] = f2bf(xf[jj]);
#pragma unroll
        for (int cf = 0; cf < 3; cf++) {
            bf16x8 b = *(const bf16x8*)(wbase + (size_t)cf * 16 * 1024 + k0);
            acc[cf] = __builtin_amdgcn_mfma_f32_16x16x32_bf16(a, b, acc[cf], 0, 0, 0);
        }
    }

#pragma unroll
    for (int cf = 0; cf < 3; cf++) {
        int gcol = wv * 48 + cf * 16 + lr;
        int m = gcol >> 6, cm = gcol & 63;
#pragma unroll
        for (int r = 0; r < 4; r++) {
            int row = rowbase + lg * 4 + r;
            short bv = f2bf(acc[cf][r]);
            if (m == 0)      Qb[(size_t)row * 64 + cm] = bv;
            else if (m == 1) Kb[(size_t)row * 64 + cm] = bv;
            else {
                int b = row >> 12, ss = row & 4095;
                Vt[(size_t)(b * 64 + cm) * S_LEN + ss] = bv;
            }
        }
    }
}

// 1 wave/block. Swapped-operand attention: S^T = mfma(K,Q), O^T = mfma(Vt, P).
__global__ __launch_bounds__(64) void attn_partial_kernel(const short* __restrict__ Qb,
        const short* __restrict__ Kb, const short* __restrict__ Vt,
        float* __restrict__ o_part, float* __restrict__ m_part, float* __restrict__ l_part,
        int G, int NPB, int C) {
    __shared__ __align__(16) char Plds[32 * 64 * 2];
    const int lane = threadIdx.x;
    const int lr = lane & 15, lg = lane >> 4;
    const int j = blockIdx.x;
    const int bb = j / NPB;
    int jb = j - bb * NPB;
    int g = 0, base = 0;
    while (jb >= base + G * (g + 1)) { base += G * (g + 1); g++; }
    int u = jb - base;
    int qdiv = u / (g + 1);
    const int qi = g * G + qdiv;
    const int cch = u - qdiv * (g + 1);
    const int qb = qi * 32;
    const int kv_start = cch * C;
    const int kv_end = min(qb + 32, kv_start + C);

    bf16x8 qa[2][2];
#pragma unroll
    for (int qf = 0; qf < 2; qf++)
#pragma unroll
        for (int dk = 0; dk < 2; dk++)
            qa[qf][dk] = *(const bf16x8*)(Qb + (size_t)(bb * S_LEN + qb + qf * 16 + lr) * 64 + dk * 32 + lg * 8);

    f32x4 o[2][4];
    float mrun[2] = {-1e30f, -1e30f}, lrun[2] = {0.f, 0.f};
#pragma unroll
    for (int qf = 0; qf < 2; qf++)
#pragma unroll
        for (int df = 0; df < 4; df++) o[qf][df] = {0.f, 0.f, 0.f, 0.f};

    const int kvb0 = kv_start >> 6, kvb1 = (kv_end + 63) >> 6;
    for (int kvb = kvb0; kvb < kvb1; kvb++) {
        const int kv0 = kvb << 6;

        bf16x8 kb[4][2], vb[2][4];
#pragma unroll
        for (int kf = 0; kf < 4; kf++)
#pragma unroll
            for (int dk = 0; dk < 2; dk++)
                kb[kf][dk] = *(const bf16x8*)(Kb + (size_t)(bb * S_LEN + kv0 + kf * 16 + lr) * 64 + dk * 32 + lg * 8);
#pragma unroll
        for (int kk = 0; kk < 2; kk++)
#pragma unroll
            for (int df = 0; df < 4; df++)
                vb[kk][df] = *(const bf16x8*)(Vt + (size_t)(bb * 64 + df * 16 + lr) * S_LEN + kv0 + kk * 32 + lg * 8);

        f32x4 s[2][4];
#pragma unroll
        for (int qf = 0; qf < 2; qf++)
#pragma unroll
            for (int kf = 0; kf < 4; kf++) {
                f32x4 z = {0.f, 0.f, 0.f, 0.f};
                z = __builtin_amdgcn_mfma_f32_16x16x32_bf16(kb[kf][0], qa[qf][0], z, 0, 0, 0);
                s[qf][kf] = __builtin_amdgcn_mfma_f32_16x16x32_bf16(kb[kf][1], qa[qf][1], z, 0, 0, 0);
            }

        const bool needmask = (kv0 + 63) > qb;
#pragma unroll
        for (int qf = 0; qf < 2; qf++)
#pragma unroll
            for (int kf = 0; kf < 4; kf++)
#pragma unroll
                for (int r = 0; r < 4; r++) {
                    float v = s[qf][kf][r] * 0.125f;
                    if (needmask) {
                        int row = qb + qf * 16 + lr;
                        int col = kv0 + kf * 16 + lg * 4 + r;
                        if (col > row) v = -1e30f;
                    }
                    s[qf][kf][r] = v;
                }

#pragma unroll
        for (int qf = 0; qf < 2; qf++) {
            float pm = -1e30f;
#pragma unroll
            for (int kf = 0; kf < 4; kf++)
#pragma unroll
                for (int r = 0; r < 4; r++) pm = fmaxf(pm, s[qf][kf][r]);
            pm = fmaxf(pm, __shfl_xor(pm, 16, 64));
            pm = fmaxf(pm, __shfl_xor(pm, 32, 64));
            float mnew = fmaxf(mrun[qf], pm);
            float fac = __expf(mrun[qf] - mnew);
            mrun[qf] = mnew;

            const int q = qf * 16 + lr;
            const int swz = (q & 7) << 4;
            float rs = 0.f;
#pragma unroll
            for (int kf = 0; kf < 4; kf++) {
                float p0 = __expf(s[qf][kf][0] - mnew);
                float p1 = __expf(s[qf][kf][1] - mnew);
                float p2 = __expf(s[qf][kf][2] - mnew);
                float p3 = __expf(s[qf][kf][3] - mnew);
                rs += (p0 + p1) + (p2 + p3);
                uint2 w; w.x = pack2bf(p0, p1); w.y = pack2bf(p2, p3);
                int byt = (q * 128 + kf * 32 + lg * 8) ^ swz;
                *(uint2*)(Plds + byt) = w;
            }
            rs += __shfl_xor(rs, 16, 64);
            rs += __shfl_xor(rs, 32, 64);
            lrun[qf] = lrun[qf] * fac + rs;
#pragma unroll
            for (int df = 0; df < 4; df++)
#pragma unroll
                for (int r = 0; r < 4; r++) o[qf][df][r] *= fac;
        }

        bf16x8 pa[2][2];
#pragma unroll
        for (int qf = 0; qf < 2; qf++)
#pragma unroll
            for (int kk = 0; kk < 2; kk++) {
                int q = qf * 16 + lr;
                int byt = (q * 128 + kk * 64 + lg * 16) ^ ((q & 7) << 4);
                pa[qf][kk] = *(const bf16x8*)(Plds + byt);
            }

#pragma unroll
        for (int qf = 0; qf < 2; qf++)
#pragma unroll
            for (int df = 0; df < 4; df++) {
                o[qf][df] = __builtin_amdgcn_mfma_f32_16x16x32_bf16(vb[0][df], pa[qf][0], o[qf][df], 0, 0, 0);
                o[qf][df] = __builtin_amdgcn_mfma_f32_16x16x32_bf16(vb[1][df], pa[qf][1], o[qf][df], 0, 0, 0);
            }
    }

#pragma unroll
    for (int qf = 0; qf < 2; qf++)
#pragma unroll
        for (int df = 0; df < 4; df++)
            *(f32x4*)(o_part + ((size_t)j * 32 + qf * 16 + lr) * 64 + df * 16 + lg * 4) = o[qf][df];
    if (lg == 0) {
#pragma unroll
        for (int qf = 0; qf < 2; qf++) {
            m_part[(size_t)j * 32 + qf * 16 + lr] = mrun[qf];
            l_part[(size_t)j * 32 + qf * 16 + lr] = lrun[qf];
        }
    }
}

// One thread per output element; m/l loads are wave-uniform, o loads coalesced.
__global__ __launch_bounds__(256) void combine_kernel(const float* __restrict__ o_part,
        const float* __restrict__ m_part, const float* __restrict__ l_part,
        float* __restrict__ out, int G, int NPB) {
    const int idx = blockIdx.x * 256 + threadIdx.x;
    const int col = idx & 63;
    const int rowg = idx >> 6;
    const int bb = rowg >> 12;
    const int srow = rowg & 4095;
    const int qi = srow >> 5;
    const int r = srow & 31;
    const int g = qi / G;
    const int n = g + 1;
    const int jb0 = bb * NPB + G * g * (g + 1) / 2 + (qi - g * G) * n;

    float M = -1e30f;
    for (int c = 0; c < n; c++) M = fmaxf(M, m_part[(size_t)(jb0 + c) * 32 + r]);
    float L = 0.f, acc = 0.f;
    for (int c = 0; c < n; c++) {
        float w = __expf(m_part[(size_t)(jb0 + c) * 32 + r] - M);
        L += l_part[(size_t)(jb0 + c) * 32 + r] * w;
        acc += o_part[((size_t)(jb0 + c) * 32 + r) * 64 + col] * w;
    }
    out[idx] = acc / L;
}

extern "C" void kernel_launch(void* const* d_in, const int* in_sizes, int n_in,
                              void* d_out, int out_size, void* d_ws, size_t ws_size,
                              hipStream_t stream) {
    const float* x  = (const float*)d_in[0];
    const float* Wq = (const float*)d_in[1];
    const float* Wk = (const float*)d_in[2];
    const float* Wv = (const float*)d_in[3];
    float* out = (float*)d_out;

    char* ws = (char*)d_ws;
    short* Wt = (short*)(ws);                   // 384 KB
    short* Qb = (short*)(ws + 0x60000);         // 2 MB
    short* Kb = (short*)(ws + 0x260000);        // 2 MB
    short* Vt = (short*)(ws + 0x460000);        // 2 MB

    // chunk tiers: C=256 (G=8, NPB=1088) -> C=512 -> C=1024, by workspace.
    int G = 8, NPB = 1088, C = 256;
    {
        size_t need = 0x660000 + (size_t)4 * NPB * 32 * 66 * 4;
        if (need > ws_size) { G = 16; NPB = 576; C = 512; }
        need = 0x660000 + (size_t)4 * NPB * 32 * 66 * 4;
        if (need > ws_size) { G = 32; NPB = 320; C = 1024; }
    }
    const int njobs = 4 * NPB;
    float* o_part = (float*)(ws + 0x660000);
    float* m_part = o_part + (size_t)njobs * 32 * 64;
    float* l_part = m_part + (size_t)njobs * 32;

    hipLaunchKernelGGL(wconv_kernel, dim3(768), dim3(256), 0, stream, Wq, Wk, Wv, Wt);
    hipLaunchKernelGGL(qkv_kernel,  dim3(1024), dim3(256), 0, stream, x, Wt, Qb, Kb, Vt);
    hipLaunchKernelGGL(attn_partial_kernel, dim3(njobs), dim3(64), 0, stream,
                       Qb, Kb, Vt, o_part, m_part, l_part, G, NPB, C);
    hipLaunchKernelGGL(combine_kernel, dim3(4096), dim3(256), 0, stream,
                       o_part, m_part, l_part, out, G, NPB);
}

// Round 6
// 130.934 us; speedup vs baseline: 1.0898x; 1.0898x over previous
//
#include <hip/hip_runtime.h>

typedef __attribute__((ext_vector_type(4))) float f32x4;
typedef __attribute__((ext_vector_type(8))) short bf16x8;

#define S_LEN 4096

__device__ inline short f2bf(float f) {
    union { float f; unsigned u; } v; v.f = f;
    unsigned r = (v.u + 0x7fffu + ((v.u >> 16) & 1u)) >> 16;
    return (short)r;
}
__device__ inline unsigned pack2bf(float a, float b) {
    return (unsigned)(unsigned short)f2bf(a) | ((unsigned)(unsigned short)f2bf(b) << 16);
}

// Wt[g][k], g = m*64 + c (m: 0=Q,1=K,2=V), from W_m[k][c] (fp32 [1024][64])
__global__ __launch_bounds__(256) void wconv_kernel(const float* __restrict__ Wq,
        const float* __restrict__ Wk, const float* __restrict__ Wv,
        short* __restrict__ Wt) {
    int idx = blockIdx.x * 256 + threadIdx.x;
    int m = idx >> 16, c = (idx >> 10) & 63, k = idx & 1023;
    const float* W = (m == 0) ? Wq : (m == 1) ? Wk : Wv;
    Wt[idx] = f2bf(W[k * 64 + c]);
}

// Barrier-free, LDS-free. Block 256 thr = 4 waves; block = 32 rows x 192 cols.
// Wave (wr,wc): rows blockIdx*32+wr*16, cols wc*96 (6 col-frags).
// Per 512-K phase: x slice -> 16 bf16x8 regs once, then 6x16 MFMAs, B from L2-hot Wt.
__global__ __launch_bounds__(256, 4) void qkv_kernel(const float* __restrict__ x,
        const short* __restrict__ Wt, short* __restrict__ Qb,
        short* __restrict__ Kb, short* __restrict__ Vt) {
    const int tid = threadIdx.x;
    const int wv = tid >> 6, lane = tid & 63;
    const int wr = wv & 1, wc = wv >> 1;
    const int lr = lane & 15, lg = lane >> 4;
    const int row16 = blockIdx.x * 32 + wr * 16;

    f32x4 acc[6];
#pragma unroll
    for (int i = 0; i < 6; i++) acc[i] = {0.f, 0.f, 0.f, 0.f};

    const float* xrow  = x + (size_t)(row16 + lr) * 1024 + lg * 8;
    const short* wbase = Wt + (size_t)(wc * 96 + lr) * 1024 + lg * 8;

#pragma unroll 1
    for (int p = 0; p < 2; p++) {
        const int kb = p * 512;
        bf16x8 a[16];
#pragma unroll
        for (int t = 0; t < 16; t++) {
            f32x4 lo = *(const f32x4*)(xrow + kb + t * 32);
            f32x4 hi = *(const f32x4*)(xrow + kb + t * 32 + 4);
            bf16x8 v;
#pragma unroll
            for (int jj = 0; jj < 4; jj++) { v[jj] = f2bf(lo[jj]); v[4 + jj] = f2bf(hi[jj]); }
            a[t] = v;
        }
#pragma unroll
        for (int t = 0; t < 16; t++) {
#pragma unroll
            for (int cf = 0; cf < 6; cf++) {
                bf16x8 b = *(const bf16x8*)(wbase + (size_t)cf * 16 * 1024 + kb + t * 32);
                acc[cf] = __builtin_amdgcn_mfma_f32_16x16x32_bf16(a[t], b, acc[cf], 0, 0, 0);
            }
        }
    }

#pragma unroll
    for (int cf = 0; cf < 6; cf++) {
        int gcol = wc * 96 + cf * 16 + lr;
        int m = gcol >> 6, cm = gcol & 63;
#pragma unroll
        for (int r = 0; r < 4; r++) {
            int row = row16 + lg * 4 + r;
            short bv = f2bf(acc[cf][r]);
            if (m == 0)      Qb[(size_t)row * 64 + cm] = bv;
            else if (m == 1) Kb[(size_t)row * 64 + cm] = bv;
            else {
                int b = row >> 12, ss = row & 4095;
                Vt[(size_t)(b * 64 + cm) * S_LEN + ss] = bv;
            }
        }
    }
}

// 1 wave/block. Swapped-operand attention: S^T = mfma(K,Q), O^T = mfma(Vt, P).
__global__ __launch_bounds__(64) void attn_partial_kernel(const short* __restrict__ Qb,
        const short* __restrict__ Kb, const short* __restrict__ Vt,
        float* __restrict__ o_part, float* __restrict__ m_part, float* __restrict__ l_part,
        int G, int NPB, int C) {
    __shared__ __align__(16) char Plds[32 * 64 * 2];
    const int lane = threadIdx.x;
    const int lr = lane & 15, lg = lane >> 4;
    const int j = blockIdx.x;
    const int bb = j / NPB;
    int jb = j - bb * NPB;
    int g = 0, base = 0;
    while (jb >= base + G * (g + 1)) { base += G * (g + 1); g++; }
    int u = jb - base;
    int qdiv = u / (g + 1);
    const int qi = g * G + qdiv;
    const int cch = u - qdiv * (g + 1);
    const int qb = qi * 32;
    const int kv_start = cch * C;
    const int kv_end = min(qb + 32, kv_start + C);

    bf16x8 qa[2][2];
#pragma unroll
    for (int qf = 0; qf < 2; qf++)
#pragma unroll
        for (int dk = 0; dk < 2; dk++)
            qa[qf][dk] = *(const bf16x8*)(Qb + (size_t)(bb * S_LEN + qb + qf * 16 + lr) * 64 + dk * 32 + lg * 8);

    f32x4 o[2][4];
    float mrun[2] = {-1e30f, -1e30f}, lrun[2] = {0.f, 0.f};
#pragma unroll
    for (int qf = 0; qf < 2; qf++)
#pragma unroll
        for (int df = 0; df < 4; df++) o[qf][df] = {0.f, 0.f, 0.f, 0.f};

    const int kvb0 = kv_start >> 6, kvb1 = (kv_end + 63) >> 6;
    for (int kvb = kvb0; kvb < kvb1; kvb++) {
        const int kv0 = kvb << 6;

        bf16x8 kb[4][2], vb[2][4];
#pragma unroll
        for (int kf = 0; kf < 4; kf++)
#pragma unroll
            for (int dk = 0; dk < 2; dk++)
                kb[kf][dk] = *(const bf16x8*)(Kb + (size_t)(bb * S_LEN + kv0 + kf * 16 + lr) * 64 + dk * 32 + lg * 8);
#pragma unroll
        for (int kk = 0; kk < 2; kk++)
#pragma unroll
            for (int df = 0; df < 4; df++)
                vb[kk][df] = *(const bf16x8*)(Vt + (size_t)(bb * 64 + df * 16 + lr) * S_LEN + kv0 + kk * 32 + lg * 8);

        f32x4 s[2][4];
#pragma unroll
        for (int qf = 0; qf < 2; qf++)
#pragma unroll
            for (int kf = 0; kf < 4; kf++) {
                f32x4 z = {0.f, 0.f, 0.f, 0.f};
                z = __builtin_amdgcn_mfma_f32_16x16x32_bf16(kb[kf][0], qa[qf][0], z, 0, 0, 0);
                s[qf][kf] = __builtin_amdgcn_mfma_f32_16x16x32_bf16(kb[kf][1], qa[qf][1], z, 0, 0, 0);
            }

        const bool needmask = (kv0 + 63) > qb;
#pragma unroll
        for (int qf = 0; qf < 2; qf++)
#pragma unroll
            for (int kf = 0; kf < 4; kf++)
#pragma unroll
                for (int r = 0; r < 4; r++) {
                    float v = s[qf][kf][r] * 0.125f;
                    if (needmask) {
                        int row = qb + qf * 16 + lr;
                        int col = kv0 + kf * 16 + lg * 4 + r;
                        if (col > row) v = -1e30f;
                    }
                    s[qf][kf][r] = v;
                }

#pragma unroll
        for (int qf = 0; qf < 2; qf++) {
            float pm = -1e30f;
#pragma unroll
            for (int kf = 0; kf < 4; kf++)
#pragma unroll
                for (int r = 0; r < 4; r++) pm = fmaxf(pm, s[qf][kf][r]);
            pm = fmaxf(pm, __shfl_xor(pm, 16, 64));
            pm = fmaxf(pm, __shfl_xor(pm, 32, 64));
            float mnew = fmaxf(mrun[qf], pm);
            float fac = __expf(mrun[qf] - mnew);
            mrun[qf] = mnew;

            const int q = qf * 16 + lr;
            const int swz = (q & 7) << 4;
            float rs = 0.f;
#pragma unroll
            for (int kf = 0; kf < 4; kf++) {
                float p0 = __expf(s[qf][kf][0] - mnew);
                float p1 = __expf(s[qf][kf][1] - mnew);
                float p2 = __expf(s[qf][kf][2] - mnew);
                float p3 = __expf(s[qf][kf][3] - mnew);
                rs += (p0 + p1) + (p2 + p3);
                uint2 w; w.x = pack2bf(p0, p1); w.y = pack2bf(p2, p3);
                int byt = (q * 128 + kf * 32 + lg * 8) ^ swz;
                *(uint2*)(Plds + byt) = w;
            }
            rs += __shfl_xor(rs, 16, 64);
            rs += __shfl_xor(rs, 32, 64);
            lrun[qf] = lrun[qf] * fac + rs;
#pragma unroll
            for (int df = 0; df < 4; df++)
#pragma unroll
                for (int r = 0; r < 4; r++) o[qf][df][r] *= fac;
        }

        bf16x8 pa[2][2];
#pragma unroll
        for (int qf = 0; qf < 2; qf++)
#pragma unroll
            for (int kk = 0; kk < 2; kk++) {
                int q = qf * 16 + lr;
                int byt = (q * 128 + kk * 64 + lg * 16) ^ ((q & 7) << 4);
                pa[qf][kk] = *(const bf16x8*)(Plds + byt);
            }

#pragma unroll
        for (int qf = 0; qf < 2; qf++)
#pragma unroll
            for (int df = 0; df < 4; df++) {
                o[qf][df] = __builtin_amdgcn_mfma_f32_16x16x32_bf16(vb[0][df], pa[qf][0], o[qf][df], 0, 0, 0);
                o[qf][df] = __builtin_amdgcn_mfma_f32_16x16x32_bf16(vb[1][df], pa[qf][1], o[qf][df], 0, 0, 0);
            }
    }

#pragma unroll
    for (int qf = 0; qf < 2; qf++)
#pragma unroll
        for (int df = 0; df < 4; df++)
            *(f32x4*)(o_part + ((size_t)j * 32 + qf * 16 + lr) * 64 + df * 16 + lg * 4) = o[qf][df];
    if (lg == 0) {
#pragma unroll
        for (int qf = 0; qf < 2; qf++) {
            m_part[(size_t)j * 32 + qf * 16 + lr] = mrun[qf];
            l_part[(size_t)j * 32 + qf * 16 + lr] = lrun[qf];
        }
    }
}

// One thread per output element; m/l loads are wave-uniform, o loads coalesced.
__global__ __launch_bounds__(256) void combine_kernel(const float* __restrict__ o_part,
        const float* __restrict__ m_part, const float* __restrict__ l_part,
        float* __restrict__ out, int G, int NPB) {
    const int idx = blockIdx.x * 256 + threadIdx.x;
    const int col = idx & 63;
    const int rowg = idx >> 6;
    const int bb = rowg >> 12;
    const int srow = rowg & 4095;
    const int qi = srow >> 5;
    const int r = srow & 31;
    const int g = qi / G;
    const int n = g + 1;
    const int jb0 = bb * NPB + G * g * (g + 1) / 2 + (qi - g * G) * n;

    float M = -1e30f;
    for (int c = 0; c < n; c++) M = fmaxf(M, m_part[(size_t)(jb0 + c) * 32 + r]);
    float L = 0.f, acc = 0.f;
    for (int c = 0; c < n; c++) {
        float w = __expf(m_part[(size_t)(jb0 + c) * 32 + r] - M);
        L += l_part[(size_t)(jb0 + c) * 32 + r] * w;
        acc += o_part[((size_t)(jb0 + c) * 32 + r) * 64 + col] * w;
    }
    out[idx] = acc / L;
}

extern "C" void kernel_launch(void* const* d_in, const int* in_sizes, int n_in,
                              void* d_out, int out_size, void* d_ws, size_t ws_size,
                              hipStream_t stream) {
    const float* x  = (const float*)d_in[0];
    const float* Wq = (const float*)d_in[1];
    const float* Wk = (const float*)d_in[2];
    const float* Wv = (const float*)d_in[3];
    float* out = (float*)d_out;

    char* ws = (char*)d_ws;
    short* Wt = (short*)(ws);                   // 384 KB
    short* Qb = (short*)(ws + 0x60000);         // 2 MB
    short* Kb = (short*)(ws + 0x260000);        // 2 MB
    short* Vt = (short*)(ws + 0x460000);        // 2 MB

    // chunk tiers: C=256 (G=8, NPB=1088) -> C=512 -> C=1024, by workspace.
    int G = 8, NPB = 1088, C = 256;
    {
        size_t need = 0x660000 + (size_t)4 * NPB * 32 * 66 * 4;
        if (need > ws_size) { G = 16; NPB = 576; C = 512; }
        need = 0x660000 + (size_t)4 * NPB * 32 * 66 * 4;
        if (need > ws_size) { G = 32; NPB = 320; C = 1024; }
    }
    const int njobs = 4 * NPB;
    float* o_part = (float*)(ws + 0x660000);
    float* m_part = o_part + (size_t)njobs * 32 * 64;
    float* l_part = m_part + (size_t)njobs * 32;

    hipLaunchKernelGGL(wconv_kernel, dim3(768), dim3(256), 0, stream, Wq, Wk, Wv, Wt);
    hipLaunchKernelGGL(qkv_kernel,  dim3(512), dim3(256), 0, stream, x, Wt, Qb, Kb, Vt);
    hipLaunchKernelGGL(attn_partial_kernel, dim3(njobs), dim3(64), 0, stream,
                       Qb, Kb, Vt, o_part, m_part, l_part, G, NPB, C);
    hipLaunchKernelGGL(combine_kernel, dim3(4096), dim3(256), 0, stream,
                       o_part, m_part, l_part, out, G, NPB);
}

// Round 7
// 120.492 us; speedup vs baseline: 1.1842x; 1.0867x over previous
//
#include <hip/hip_runtime.h>

typedef __attribute__((ext_vector_type(4))) float f32x4;
typedef __attribute__((ext_vector_type(8))) short bf16x8;

#define S_LEN 4096

__device__ inline short f2bf(float f) {
    union { float f; unsigned u; } v; v.f = f;
    unsigned r = (v.u + 0x7fffu + ((v.u >> 16) & 1u)) >> 16;
    return (short)r;
}
__device__ inline unsigned pack2bf(float a, float b) {
    return (unsigned)(unsigned short)f2bf(a) | ((unsigned)(unsigned short)f2bf(b) << 16);
}
__device__ inline void gload_lds16(const void* g, void* l) {
    __builtin_amdgcn_global_load_lds(
        (const __attribute__((address_space(1))) unsigned int*)g,
        (__attribute__((address_space(3))) unsigned int*)l, 16, 0, 0);
}

// Wt[g][k], g = m*64 + c (m: 0=Q,1=K,2=V), from W_m[k][c] (fp32 [1024][64])
__global__ __launch_bounds__(256) void wconv_kernel(const float* __restrict__ Wq,
        const float* __restrict__ Wk, const float* __restrict__ Wv,
        short* __restrict__ Wt) {
    int idx = blockIdx.x * 256 + threadIdx.x;
    int m = idx >> 16, c = (idx >> 10) & 63, k = idx & 1023;
    const float* W = (m == 0) ? Wq : (m == 1) ? Wk : Wv;
    Wt[idx] = f2bf(W[k * 64 + c]);
}

// Deep-pipelined staging GEMM: block = 4 waves, 16 rows x 192 cols (wave w: cols w*48..+47).
// K-step 64: x tile [16][64] fp32 = 4 KB/stage, 6 stages, prefetch depth 3, counted vmcnt.
// LDS 16B-chunk XOR swizzle (chunk ^= row&7) applied on BOTH stage-source and ds_read.
__global__ __launch_bounds__(256, 3) void qkv_kernel(const float* __restrict__ x,
        const short* __restrict__ Wt, short* __restrict__ Qb,
        short* __restrict__ Kb, short* __restrict__ Vt) {
    __shared__ __align__(16) float xs[6][16 * 64];   // 24 KB
    const int tid = threadIdx.x;
    const int wv = tid >> 6, lane = tid & 63;
    const int lr = lane & 15, lg = lane >> 4;
    const int rowbase = blockIdx.x * 16;

    f32x4 acc[3];
#pragma unroll
    for (int i = 0; i < 3; i++) acc[i] = {0.f, 0.f, 0.f, 0.f};

    // staging: thread -> row tid>>4, LDS chunk tid&15; global chunk = cL ^ (row&7)
    const int srow = tid >> 4, scL = tid & 15;
    const float* sg = x + (size_t)(rowbase + srow) * 1024 + (scL ^ (srow & 7)) * 4;
    char* sl = (char*)xs + tid * 16;                 // + stage*4096

    const short* wbase = Wt + (size_t)(wv * 48 + lr) * 1024 + lg * 8;
    const int swz = lr & 7;

#pragma unroll
    for (int s = 0; s < 3; s++) gload_lds16(sg + s * 64, sl + s * 4096);

#pragma unroll
    for (int t = 0; t < 16; t++) {
        if (t <= 13)      asm volatile("s_waitcnt vmcnt(2)" ::: "memory");
        else if (t == 14) asm volatile("s_waitcnt vmcnt(1)" ::: "memory");
        else              asm volatile("s_waitcnt vmcnt(0)" ::: "memory");
        __builtin_amdgcn_sched_barrier(0);
        __builtin_amdgcn_s_barrier();
        __builtin_amdgcn_sched_barrier(0);
        if (t + 3 < 16) gload_lds16(sg + (t + 3) * 64, sl + ((t + 3) % 6) * 4096);

        const char* xb = (const char*)&xs[t % 6][0] + lr * 256;
#pragma unroll
        for (int kh = 0; kh < 2; kh++) {
            const int c0 = kh * 8 + lg * 2;
            f32x4 a0 = *(const f32x4*)(xb + (((c0    ) ^ swz) << 4));
            f32x4 a1 = *(const f32x4*)(xb + (((c0 + 1) ^ swz) << 4));
            bf16x8 a;
#pragma unroll
            for (int jj = 0; jj < 4; jj++) { a[jj] = f2bf(a0[jj]); a[4 + jj] = f2bf(a1[jj]); }
#pragma unroll
            for (int cf = 0; cf < 3; cf++) {
                bf16x8 b = *(const bf16x8*)(wbase + (size_t)cf * 16 * 1024 + t * 64 + kh * 32);
                acc[cf] = __builtin_amdgcn_mfma_f32_16x16x32_bf16(a, b, acc[cf], 0, 0, 0);
            }
        }
        __builtin_amdgcn_sched_barrier(0);
    }

#pragma unroll
    for (int cf = 0; cf < 3; cf++) {
        int gcol = wv * 48 + cf * 16 + lr;
        int m = gcol >> 6, cm = gcol & 63;
#pragma unroll
        for (int r = 0; r < 4; r++) {
            int row = rowbase + lg * 4 + r;
            short bv = f2bf(acc[cf][r]);
            if (m == 0)      Qb[(size_t)row * 64 + cm] = bv;
            else if (m == 1) Kb[(size_t)row * 64 + cm] = bv;
            else {
                int b = row >> 12, ss = row & 4095;
                Vt[(size_t)(b * 64 + cm) * S_LEN + ss] = bv;
            }
        }
    }
}

// 1 wave/block. Swapped-operand attention: S^T = mfma(K,Q), O^T = mfma(Vt, P).
__global__ __launch_bounds__(64) void attn_partial_kernel(const short* __restrict__ Qb,
        const short* __restrict__ Kb, const short* __restrict__ Vt,
        float* __restrict__ o_part, float* __restrict__ m_part, float* __restrict__ l_part,
        int G, int NPB, int C) {
    __shared__ __align__(16) char Plds[32 * 64 * 2];
    const int lane = threadIdx.x;
    const int lr = lane & 15, lg = lane >> 4;
    const int j = blockIdx.x;
    const int bb = j / NPB;
    int jb = j - bb * NPB;
    int g = 0, base = 0;
    while (jb >= base + G * (g + 1)) { base += G * (g + 1); g++; }
    int u = jb - base;
    int qdiv = u / (g + 1);
    const int qi = g * G + qdiv;
    const int cch = u - qdiv * (g + 1);
    const int qb = qi * 32;
    const int kv_start = cch * C;
    const int kv_end = min(qb + 32, kv_start + C);

    bf16x8 qa[2][2];
#pragma unroll
    for (int qf = 0; qf < 2; qf++)
#pragma unroll
        for (int dk = 0; dk < 2; dk++)
            qa[qf][dk] = *(const bf16x8*)(Qb + (size_t)(bb * S_LEN + qb + qf * 16 + lr) * 64 + dk * 32 + lg * 8);

    f32x4 o[2][4];
    float mrun[2] = {-1e30f, -1e30f}, lrun[2] = {0.f, 0.f};
#pragma unroll
    for (int qf = 0; qf < 2; qf++)
#pragma unroll
        for (int df = 0; df < 4; df++) o[qf][df] = {0.f, 0.f, 0.f, 0.f};

    const int kvb0 = kv_start >> 6, kvb1 = (kv_end + 63) >> 6;
    for (int kvb = kvb0; kvb < kvb1; kvb++) {
        const int kv0 = kvb << 6;

        bf16x8 kb[4][2], vb[2][4];
#pragma unroll
        for (int kf = 0; kf < 4; kf++)
#pragma unroll
            for (int dk = 0; dk < 2; dk++)
                kb[kf][dk] = *(const bf16x8*)(Kb + (size_t)(bb * S_LEN + kv0 + kf * 16 + lr) * 64 + dk * 32 + lg * 8);
#pragma unroll
        for (int kk = 0; kk < 2; kk++)
#pragma unroll
            for (int df = 0; df < 4; df++)
                vb[kk][df] = *(const bf16x8*)(Vt + (size_t)(bb * 64 + df * 16 + lr) * S_LEN + kv0 + kk * 32 + lg * 8);

        f32x4 s[2][4];
#pragma unroll
        for (int qf = 0; qf < 2; qf++)
#pragma unroll
            for (int kf = 0; kf < 4; kf++) {
                f32x4 z = {0.f, 0.f, 0.f, 0.f};
                z = __builtin_amdgcn_mfma_f32_16x16x32_bf16(kb[kf][0], qa[qf][0], z, 0, 0, 0);
                s[qf][kf] = __builtin_amdgcn_mfma_f32_16x16x32_bf16(kb[kf][1], qa[qf][1], z, 0, 0, 0);
            }

        const bool needmask = (kv0 + 63) > qb;
#pragma unroll
        for (int qf = 0; qf < 2; qf++)
#pragma unroll
            for (int kf = 0; kf < 4; kf++)
#pragma unroll
                for (int r = 0; r < 4; r++) {
                    float v = s[qf][kf][r] * 0.125f;
                    if (needmask) {
                        int row = qb + qf * 16 + lr;
                        int col = kv0 + kf * 16 + lg * 4 + r;
                        if (col > row) v = -1e30f;
                    }
                    s[qf][kf][r] = v;
                }

#pragma unroll
        for (int qf = 0; qf < 2; qf++) {
            float pm = -1e30f;
#pragma unroll
            for (int kf = 0; kf < 4; kf++)
#pragma unroll
                for (int r = 0; r < 4; r++) pm = fmaxf(pm, s[qf][kf][r]);
            pm = fmaxf(pm, __shfl_xor(pm, 16, 64));
            pm = fmaxf(pm, __shfl_xor(pm, 32, 64));
            float mnew = fmaxf(mrun[qf], pm);
            float fac = __expf(mrun[qf] - mnew);
            mrun[qf] = mnew;

            const int q = qf * 16 + lr;
            const int swz = (q & 7) << 4;
            float rs = 0.f;
#pragma unroll
            for (int kf = 0; kf < 4; kf++) {
                float p0 = __expf(s[qf][kf][0] - mnew);
                float p1 = __expf(s[qf][kf][1] - mnew);
                float p2 = __expf(s[qf][kf][2] - mnew);
                float p3 = __expf(s[qf][kf][3] - mnew);
                rs += (p0 + p1) + (p2 + p3);
                uint2 w; w.x = pack2bf(p0, p1); w.y = pack2bf(p2, p3);
                int byt = (q * 128 + kf * 32 + lg * 8) ^ swz;
                *(uint2*)(Plds + byt) = w;
            }
            rs += __shfl_xor(rs, 16, 64);
            rs += __shfl_xor(rs, 32, 64);
            lrun[qf] = lrun[qf] * fac + rs;
#pragma unroll
            for (int df = 0; df < 4; df++)
#pragma unroll
                for (int r = 0; r < 4; r++) o[qf][df][r] *= fac;
        }

        bf16x8 pa[2][2];
#pragma unroll
        for (int qf = 0; qf < 2; qf++)
#pragma unroll
            for (int kk = 0; kk < 2; kk++) {
                int q = qf * 16 + lr;
                int byt = (q * 128 + kk * 64 + lg * 16) ^ ((q & 7) << 4);
                pa[qf][kk] = *(const bf16x8*)(Plds + byt);
            }

#pragma unroll
        for (int qf = 0; qf < 2; qf++)
#pragma unroll
            for (int df = 0; df < 4; df++) {
                o[qf][df] = __builtin_amdgcn_mfma_f32_16x16x32_bf16(vb[0][df], pa[qf][0], o[qf][df], 0, 0, 0);
                o[qf][df] = __builtin_amdgcn_mfma_f32_16x16x32_bf16(vb[1][df], pa[qf][1], o[qf][df], 0, 0, 0);
            }
    }

#pragma unroll
    for (int qf = 0; qf < 2; qf++)
#pragma unroll
        for (int df = 0; df < 4; df++)
            *(f32x4*)(o_part + ((size_t)j * 32 + qf * 16 + lr) * 64 + df * 16 + lg * 4) = o[qf][df];
    if (lg == 0) {
#pragma unroll
        for (int qf = 0; qf < 2; qf++) {
            m_part[(size_t)j * 32 + qf * 16 + lr] = mrun[qf];
            l_part[(size_t)j * 32 + qf * 16 + lr] = lrun[qf];
        }
    }
}

// One thread per output element; m/l loads are wave-uniform, o loads coalesced.
__global__ __launch_bounds__(256) void combine_kernel(const float* __restrict__ o_part,
        const float* __restrict__ m_part, const float* __restrict__ l_part,
        float* __restrict__ out, int G, int NPB) {
    const int idx = blockIdx.x * 256 + threadIdx.x;
    const int col = idx & 63;
    const int rowg = idx >> 6;
    const int bb = rowg >> 12;
    const int srow = rowg & 4095;
    const int qi = srow >> 5;
    const int r = srow & 31;
    const int g = qi / G;
    const int n = g + 1;
    const int jb0 = bb * NPB + G * g * (g + 1) / 2 + (qi - g * G) * n;

    float M = -1e30f;
    for (int c = 0; c < n; c++) M = fmaxf(M, m_part[(size_t)(jb0 + c) * 32 + r]);
    float L = 0.f, acc = 0.f;
    for (int c = 0; c < n; c++) {
        float w = __expf(m_part[(size_t)(jb0 + c) * 32 + r] - M);
        L += l_part[(size_t)(jb0 + c) * 32 + r] * w;
        acc += o_part[((size_t)(jb0 + c) * 32 + r) * 64 + col] * w;
    }
    out[idx] = acc / L;
}

extern "C" void kernel_launch(void* const* d_in, const int* in_sizes, int n_in,
                              void* d_out, int out_size, void* d_ws, size_t ws_size,
                              hipStream_t stream) {
    const float* x  = (const float*)d_in[0];
    const float* Wq = (const float*)d_in[1];
    const float* Wk = (const float*)d_in[2];
    const float* Wv = (const float*)d_in[3];
    float* out = (float*)d_out;

    char* ws = (char*)d_ws;
    short* Wt = (short*)(ws);                   // 384 KB
    short* Qb = (short*)(ws + 0x60000);         // 2 MB
    short* Kb = (short*)(ws + 0x260000);        // 2 MB
    short* Vt = (short*)(ws + 0x460000);        // 2 MB

    // chunk tiers: C=256 (G=8, NPB=1088) -> C=512 -> C=1024, by workspace.
    int G = 8, NPB = 1088, C = 256;
    {
        size_t need = 0x660000 + (size_t)4 * NPB * 32 * 66 * 4;
        if (need > ws_size) { G = 16; NPB = 576; C = 512; }
        need = 0x660000 + (size_t)4 * NPB * 32 * 66 * 4;
        if (need > ws_size) { G = 32; NPB = 320; C = 1024; }
    }
    const int njobs = 4 * NPB;
    float* o_part = (float*)(ws + 0x660000);
    float* m_part = o_part + (size_t)njobs * 32 * 64;
    float* l_part = m_part + (size_t)njobs * 32;

    hipLaunchKernelGGL(wconv_kernel, dim3(768), dim3(256), 0, stream, Wq, Wk, Wv, Wt);
    hipLaunchKernelGGL(qkv_kernel,  dim3(1024), dim3(256), 0, stream, x, Wt, Qb, Kb, Vt);
    hipLaunchKernelGGL(attn_partial_kernel, dim3(njobs), dim3(64), 0, stream,
                       Qb, Kb, Vt, o_part, m_part, l_part, G, NPB, C);
    hipLaunchKernelGGL(combine_kernel, dim3(4096), dim3(256), 0, stream,
                       o_part, m_part, l_part, out, G, NPB);
}

// Round 8
// 87.389 us; speedup vs baseline: 1.6328x; 1.3788x over previous
//
#include <hip/hip_runtime.h>

typedef __attribute__((ext_vector_type(4))) float f32x4;
typedef __attribute__((ext_vector_type(8))) short bf16x8;

#define S_LEN 4096

__device__ inline short f2bf(float f) {
    union { float f; unsigned u; } v; v.f = f;
    unsigned r = (v.u + 0x7fffu + ((v.u >> 16) & 1u)) >> 16;
    return (short)r;
}
__device__ inline unsigned pack2bf(float a, float b) {
    return (unsigned)(unsigned short)f2bf(a) | ((unsigned)(unsigned short)f2bf(b) << 16);
}
__device__ inline void gload_lds16(const void* g, void* l) {
    __builtin_amdgcn_global_load_lds(
        (const __attribute__((address_space(1))) unsigned int*)g,
        (__attribute__((address_space(3))) unsigned int*)l, 16, 0, 0);
}

// Pre-swizzled B: for K-step t, row g (=m*64+c), chunkP (16B = 8 bf16), e8:
//   Wsz[t*12288 + row*64 + chunkP*8 + e8] = bf16( W_m[k][c] ),
//   k = t*64 + (chunkP ^ (row&7))*8 + e8.
// Staged LINEARLY into LDS; read back with byte ^ ((row&7)<<4) -> correct B-frags.
__global__ __launch_bounds__(256) void wconv_kernel(const float* __restrict__ Wq,
        const float* __restrict__ Wk, const float* __restrict__ Wv,
        short* __restrict__ Wsz) {
    int idx = blockIdx.x * 256 + threadIdx.x;          // 0..196607
    int t = idx / 12288;
    int rem = idx - t * 12288;
    int row = rem >> 6;
    int rr = rem & 63;
    int chP = rr >> 3, e8 = rr & 7;
    int k = t * 64 + ((chP ^ (row & 7)) << 3) + e8;
    int m = row >> 6, c = row & 63;
    const float* W = (m == 0) ? Wq : (m == 1) ? Wk : Wv;
    Wsz[idx] = f2bf(W[k * 64 + c]);
}

// Pipelined GEMM, both operands in LDS. Block 512 thr = 8 waves; 64 rows x 192 cols.
// Wave (wr=wv>>2, wc=wv&3): rows wr*32 (2 frags), cols wc*48 (3 frags).
// Stage (K=64): A[64][64] f32 16KB (XOR-preswizzled source) + B[192][64] bf16 24KB
// (from pre-swizzled Wsz). Triple-buffer, 1 barrier/iter, counted vmcnt(5).
__global__ __launch_bounds__(512, 2) void qkv_kernel(const float* __restrict__ x,
        const short* __restrict__ Wsz, short* __restrict__ Qb,
        short* __restrict__ Kb, short* __restrict__ Vt) {
    __shared__ __align__(16) char lds[3][40960];       // 120 KB: A 16K | B 24K
    const int tid = threadIdx.x;
    const int wv = tid >> 6, lane = tid & 63;
    const int wc = wv & 3, wr = wv >> 2;
    const int lr = lane & 15, lg = lane >> 4;
    const int rowbase = blockIdx.x * 64;

    f32x4 acc[2][3];
#pragma unroll
    for (int i = 0; i < 2; i++)
#pragma unroll
        for (int jc = 0; jc < 3; jc++) acc[i][jc] = {0.f, 0.f, 0.f, 0.f};

    // A staging: thread covers LDS bytes tid*16 (+8192): byte p -> row p>>8, chunkP (p>>4)&15
    const int aoff0 = tid * 16, aoff1 = tid * 16 + 8192;
    const int arow0 = aoff0 >> 8, achP0 = (aoff0 >> 4) & 15;
    const int arow1 = aoff1 >> 8, achP1 = (aoff1 >> 4) & 15;
    const float* asrc0 = x + (size_t)(rowbase + arow0) * 1024 + ((achP0 ^ (arow0 & 7)) << 2);
    const float* asrc1 = x + (size_t)(rowbase + arow1) * 1024 + ((achP1 ^ (arow1 & 7)) << 2);
    const char* bsrc = (const char*)Wsz + tid * 16;

#define STAGE(t_)                                                         \
    {                                                                     \
        char* base_ = lds[(t_) % 3];                                      \
        gload_lds16(asrc0 + (t_) * 64, base_ + aoff0);                    \
        gload_lds16(asrc1 + (t_) * 64, base_ + aoff1);                    \
        const char* bs_ = bsrc + (t_) * 24576;                            \
        gload_lds16(bs_,         base_ + 16384 + tid * 16);               \
        gload_lds16(bs_ + 8192,  base_ + 16384 + tid * 16 + 8192);        \
        gload_lds16(bs_ + 16384, base_ + 16384 + tid * 16 + 16384);       \
    }

    STAGE(0);
    STAGE(1);

#pragma unroll
    for (int t = 0; t < 16; t++) {
        if (t < 15) asm volatile("s_waitcnt vmcnt(5)" ::: "memory");
        else        asm volatile("s_waitcnt vmcnt(0)" ::: "memory");
        __builtin_amdgcn_sched_barrier(0);
        __builtin_amdgcn_s_barrier();
        __builtin_amdgcn_sched_barrier(0);
        if (t + 2 < 16) STAGE(t + 2);

        const char* Ab = lds[t % 3];
        const char* Bb = lds[t % 3] + 16384;
#pragma unroll
        for (int kh = 0; kh < 2; kh++) {
            const int c0 = kh * 8 + lg * 2;
            bf16x8 a[2];
#pragma unroll
            for (int rf = 0; rf < 2; rf++) {
                int row = wr * 32 + rf * 16 + lr;
                int sw = row & 7;
                f32x4 a0 = *(const f32x4*)(Ab + row * 256 + ((c0 ^ sw) << 4));
                f32x4 a1 = *(const f32x4*)(Ab + row * 256 + (((c0 + 1) ^ sw) << 4));
                bf16x8 v;
#pragma unroll
                for (int jj = 0; jj < 4; jj++) { v[jj] = f2bf(a0[jj]); v[4 + jj] = f2bf(a1[jj]); }
                a[rf] = v;
            }
            const int bch = kh * 4 + lg;
#pragma unroll
            for (int cf = 0; cf < 3; cf++) {
                int brow = wc * 48 + cf * 16 + lr;
                bf16x8 b = *(const bf16x8*)(Bb + brow * 128 + ((bch ^ (brow & 7)) << 4));
                acc[0][cf] = __builtin_amdgcn_mfma_f32_16x16x32_bf16(a[0], b, acc[0][cf], 0, 0, 0);
                acc[1][cf] = __builtin_amdgcn_mfma_f32_16x16x32_bf16(a[1], b, acc[1][cf], 0, 0, 0);
            }
        }
        __builtin_amdgcn_sched_barrier(0);
    }
#undef STAGE

#pragma unroll
    for (int cf = 0; cf < 3; cf++) {
        int gcol = wc * 48 + cf * 16 + lr;
        int m = gcol >> 6, cm = gcol & 63;
#pragma unroll
        for (int rf = 0; rf < 2; rf++)
#pragma unroll
            for (int r = 0; r < 4; r++) {
                int row = rowbase + wr * 32 + rf * 16 + lg * 4 + r;
                short bv = f2bf(acc[rf][cf][r]);
                if (m == 0)      Qb[(size_t)row * 64 + cm] = bv;
                else if (m == 1) Kb[(size_t)row * 64 + cm] = bv;
                else {
                    int b = row >> 12, ss = row & 4095;
                    Vt[(size_t)(b * 64 + cm) * S_LEN + ss] = bv;
                }
            }
    }
}

// 1 wave/block. Swapped-operand attention: S^T = mfma(K,Q), O^T = mfma(Vt, P).
__global__ __launch_bounds__(64) void attn_partial_kernel(const short* __restrict__ Qb,
        const short* __restrict__ Kb, const short* __restrict__ Vt,
        float* __restrict__ o_part, float* __restrict__ m_part, float* __restrict__ l_part,
        int G, int NPB, int C) {
    __shared__ __align__(16) char Plds[32 * 64 * 2];
    const int lane = threadIdx.x;
    const int lr = lane & 15, lg = lane >> 4;
    const int j = blockIdx.x;
    const int bb = j / NPB;
    int jb = j - bb * NPB;
    int g = 0, base = 0;
    while (jb >= base + G * (g + 1)) { base += G * (g + 1); g++; }
    int u = jb - base;
    int qdiv = u / (g + 1);
    const int qi = g * G + qdiv;
    const int cch = u - qdiv * (g + 1);
    const int qb = qi * 32;
    const int kv_start = cch * C;
    const int kv_end = min(qb + 32, kv_start + C);

    bf16x8 qa[2][2];
#pragma unroll
    for (int qf = 0; qf < 2; qf++)
#pragma unroll
        for (int dk = 0; dk < 2; dk++)
            qa[qf][dk] = *(const bf16x8*)(Qb + (size_t)(bb * S_LEN + qb + qf * 16 + lr) * 64 + dk * 32 + lg * 8);

    f32x4 o[2][4];
    float mrun[2] = {-1e30f, -1e30f}, lrun[2] = {0.f, 0.f};
#pragma unroll
    for (int qf = 0; qf < 2; qf++)
#pragma unroll
        for (int df = 0; df < 4; df++) o[qf][df] = {0.f, 0.f, 0.f, 0.f};

    const int kvb0 = kv_start >> 6, kvb1 = (kv_end + 63) >> 6;
    for (int kvb = kvb0; kvb < kvb1; kvb++) {
        const int kv0 = kvb << 6;

        bf16x8 kb[4][2], vb[2][4];
#pragma unroll
        for (int kf = 0; kf < 4; kf++)
#pragma unroll
            for (int dk = 0; dk < 2; dk++)
                kb[kf][dk] = *(const bf16x8*)(Kb + (size_t)(bb * S_LEN + kv0 + kf * 16 + lr) * 64 + dk * 32 + lg * 8);
#pragma unroll
        for (int kk = 0; kk < 2; kk++)
#pragma unroll
            for (int df = 0; df < 4; df++)
                vb[kk][df] = *(const bf16x8*)(Vt + (size_t)(bb * 64 + df * 16 + lr) * S_LEN + kv0 + kk * 32 + lg * 8);

        f32x4 s[2][4];
#pragma unroll
        for (int qf = 0; qf < 2; qf++)
#pragma unroll
            for (int kf = 0; kf < 4; kf++) {
                f32x4 z = {0.f, 0.f, 0.f, 0.f};
                z = __builtin_amdgcn_mfma_f32_16x16x32_bf16(kb[kf][0], qa[qf][0], z, 0, 0, 0);
                s[qf][kf] = __builtin_amdgcn_mfma_f32_16x16x32_bf16(kb[kf][1], qa[qf][1], z, 0, 0, 0);
            }

        const bool needmask = (kv0 + 63) > qb;
#pragma unroll
        for (int qf = 0; qf < 2; qf++)
#pragma unroll
            for (int kf = 0; kf < 4; kf++)
#pragma unroll
                for (int r = 0; r < 4; r++) {
                    float v = s[qf][kf][r] * 0.125f;
                    if (needmask) {
                        int row = qb + qf * 16 + lr;
                        int col = kv0 + kf * 16 + lg * 4 + r;
                        if (col > row) v = -1e30f;
                    }
                    s[qf][kf][r] = v;
                }

#pragma unroll
        for (int qf = 0; qf < 2; qf++) {
            float pm = -1e30f;
#pragma unroll
            for (int kf = 0; kf < 4; kf++)
#pragma unroll
                for (int r = 0; r < 4; r++) pm = fmaxf(pm, s[qf][kf][r]);
            pm = fmaxf(pm, __shfl_xor(pm, 16, 64));
            pm = fmaxf(pm, __shfl_xor(pm, 32, 64));
            float mnew = fmaxf(mrun[qf], pm);
            float fac = __expf(mrun[qf] - mnew);
            mrun[qf] = mnew;

            const int q = qf * 16 + lr;
            const int swz = (q & 7) << 4;
            float rs = 0.f;
#pragma unroll
            for (int kf = 0; kf < 4; kf++) {
                float p0 = __expf(s[qf][kf][0] - mnew);
                float p1 = __expf(s[qf][kf][1] - mnew);
                float p2 = __expf(s[qf][kf][2] - mnew);
                float p3 = __expf(s[qf][kf][3] - mnew);
                rs += (p0 + p1) + (p2 + p3);
                uint2 w; w.x = pack2bf(p0, p1); w.y = pack2bf(p2, p3);
                int byt = (q * 128 + kf * 32 + lg * 8) ^ swz;
                *(uint2*)(Plds + byt) = w;
            }
            rs += __shfl_xor(rs, 16, 64);
            rs += __shfl_xor(rs, 32, 64);
            lrun[qf] = lrun[qf] * fac + rs;
#pragma unroll
            for (int df = 0; df < 4; df++)
#pragma unroll
                for (int r = 0; r < 4; r++) o[qf][df][r] *= fac;
        }

        bf16x8 pa[2][2];
#pragma unroll
        for (int qf = 0; qf < 2; qf++)
#pragma unroll
            for (int kk = 0; kk < 2; kk++) {
                int q = qf * 16 + lr;
                int byt = (q * 128 + kk * 64 + lg * 16) ^ ((q & 7) << 4);
                pa[qf][kk] = *(const bf16x8*)(Plds + byt);
            }

#pragma unroll
        for (int qf = 0; qf < 2; qf++)
#pragma unroll
            for (int df = 0; df < 4; df++) {
                o[qf][df] = __builtin_amdgcn_mfma_f32_16x16x32_bf16(vb[0][df], pa[qf][0], o[qf][df], 0, 0, 0);
                o[qf][df] = __builtin_amdgcn_mfma_f32_16x16x32_bf16(vb[1][df], pa[qf][1], o[qf][df], 0, 0, 0);
            }
    }

#pragma unroll
    for (int qf = 0; qf < 2; qf++)
#pragma unroll
        for (int df = 0; df < 4; df++)
            *(f32x4*)(o_part + ((size_t)j * 32 + qf * 16 + lr) * 64 + df * 16 + lg * 4) = o[qf][df];
    if (lg == 0) {
#pragma unroll
        for (int qf = 0; qf < 2; qf++) {
            m_part[(size_t)j * 32 + qf * 16 + lr] = mrun[qf];
            l_part[(size_t)j * 32 + qf * 16 + lr] = lrun[qf];
        }
    }
}

// One thread per output element; m/l loads are wave-uniform, o loads coalesced.
__global__ __launch_bounds__(256) void combine_kernel(const float* __restrict__ o_part,
        const float* __restrict__ m_part, const float* __restrict__ l_part,
        float* __restrict__ out, int G, int NPB) {
    const int idx = blockIdx.x * 256 + threadIdx.x;
    const int col = idx & 63;
    const int rowg = idx >> 6;
    const int bb = rowg >> 12;
    const int srow = rowg & 4095;
    const int qi = srow >> 5;
    const int r = srow & 31;
    const int g = qi / G;
    const int n = g + 1;
    const int jb0 = bb * NPB + G * g * (g + 1) / 2 + (qi - g * G) * n;

    float M = -1e30f;
    for (int c = 0; c < n; c++) M = fmaxf(M, m_part[(size_t)(jb0 + c) * 32 + r]);
    float L = 0.f, acc = 0.f;
    for (int c = 0; c < n; c++) {
        float w = __expf(m_part[(size_t)(jb0 + c) * 32 + r] - M);
        L += l_part[(size_t)(jb0 + c) * 32 + r] * w;
        acc += o_part[((size_t)(jb0 + c) * 32 + r) * 64 + col] * w;
    }
    out[idx] = acc / L;
}

extern "C" void kernel_launch(void* const* d_in, const int* in_sizes, int n_in,
                              void* d_out, int out_size, void* d_ws, size_t ws_size,
                              hipStream_t stream) {
    const float* x  = (const float*)d_in[0];
    const float* Wq = (const float*)d_in[1];
    const float* Wk = (const float*)d_in[2];
    const float* Wv = (const float*)d_in[3];
    float* out = (float*)d_out;

    char* ws = (char*)d_ws;
    short* Wsz = (short*)(ws);                  // 384 KB (swizzled layout)
    short* Qb = (short*)(ws + 0x60000);         // 2 MB
    short* Kb = (short*)(ws + 0x260000);        // 2 MB
    short* Vt = (short*)(ws + 0x460000);        // 2 MB

    // chunk tiers: C=256 (G=8, NPB=1088) -> C=512 -> C=1024, by workspace.
    int G = 8, NPB = 1088, C = 256;
    {
        size_t need = 0x660000 + (size_t)4 * NPB * 32 * 66 * 4;
        if (need > ws_size) { G = 16; NPB = 576; C = 512; }
        need = 0x660000 + (size_t)4 * NPB * 32 * 66 * 4;
        if (need > ws_size) { G = 32; NPB = 320; C = 1024; }
    }
    const int njobs = 4 * NPB;
    float* o_part = (float*)(ws + 0x660000);
    float* m_part = o_part + (size_t)njobs * 32 * 64;
    float* l_part = m_part + (size_t)njobs * 32;

    hipLaunchKernelGGL(wconv_kernel, dim3(768), dim3(256), 0, stream, Wq, Wk, Wv, Wsz);
    hipLaunchKernelGGL(qkv_kernel,  dim3(256), dim3(512), 0, stream, x, Wsz, Qb, Kb, Vt);
    hipLaunchKernelGGL(attn_partial_kernel, dim3(njobs), dim3(64), 0, stream,
                       Qb, Kb, Vt, o_part, m_part, l_part, G, NPB, C);
    hipLaunchKernelGGL(combine_kernel, dim3(4096), dim3(256), 0, stream,
                       o_part, m_part, l_part, out, G, NPB);
}